// Round 5
// baseline (459.294 us; speedup 1.0000x reference)
//
#include <hip/hip_runtime.h>

// LSTM scan, B=8192 chains, T=2048 steps, D=H=2.
// 4 lanes per element (quad), DPP quad_perm cross-lane (round 2),
// exp2-based nonlinearities (round 3 — Pade regressed, reverted),
// register double-buffered x (round 3), and NEW in round 5:
// 2 independent chains interleaved per thread (ILP fills the serial
// dependency-chain stall slots that TLP can't, since occupancy is
// 1 wave/SIMD).

#define LOG2E 1.4426950408889634f

template <int CTRL>
__device__ __forceinline__ float qperm(float v) {
    int i = __builtin_bit_cast(int, v);
    i = __builtin_amdgcn_update_dpp(0, i, CTRL, 0xf, 0xf, true);
    return __builtin_bit_cast(float, i);
}
#define QP_BCAST0 0x00  // (0,0,0,0)
#define QP_BCAST1 0x55  // (1,1,1,1)
#define QP_SWAP2  0x4E  // (2,3,0,1)

__global__ __launch_bounds__(64, 1) void lstm_quad_ilp2_kernel(
    const float* __restrict__ x,
    const float* __restrict__ h0,
    const float* __restrict__ c0,
    const float* __restrict__ w_ih,
    const float* __restrict__ w_hh,
    const float* __restrict__ b_ih,
    const float* __restrict__ b_hh,
    float* __restrict__ out,
    int B, int T)
{
    const int tid = blockIdx.x * blockDim.x + threadIdx.x;
    const int p = tid >> 2;        // chain pair index
    const int q = tid & 3;         // lane within quad
    if (p >= B / 2) return;
    const int e0 = 2 * p;          // chain 0 element
    const int e1 = 2 * p + 1;      // chain 1 element (adjacent row)

    // slotA rows: q0->i0(0) q1->i1(1) q2->g0(4) q3->g1(5); slotB = +2
    const int rA = (q < 2) ? q : q + 2;
    const int rB = rA + 2;

    const float wiA0 = w_ih[2 * rA], wiA1 = w_ih[2 * rA + 1];
    const float whA0 = w_hh[2 * rA], whA1 = w_hh[2 * rA + 1];
    const float biasA = b_ih[rA] + b_hh[rA];
    const float wiB0 = w_ih[2 * rB], wiB1 = w_ih[2 * rB + 1];
    const float whB0 = w_hh[2 * rB], whB1 = w_hh[2 * rB + 1];
    const float biasB = b_ih[rB] + b_hh[rB];

    // slotA nonlinearity: sigma (q0,q1) / tanh (q2,q3):
    // n = m * rcp(1 + exp2(a*g)) + d
    const bool isTanh = (q >= 2);
    const float aA = isTanh ? (2.0f * LOG2E) : (-LOG2E);
    const float mA = isTanh ? -2.0f : 1.0f;
    const float dA = isTanh ? 1.0f : 0.0f;

    float hU = h0[2 * e0 + (q & 1)], cU = c0[2 * e0 + (q & 1)];
    float hV = h0[2 * e1 + (q & 1)], cV = c0[2 * e1 + (q & 1)];

    const int NI = T >> 1;  // float4s per row (2 timesteps each)
    const float4* __restrict__ xpU =
        reinterpret_cast<const float4*>(x) + (size_t)e0 * NI;
    const float4* __restrict__ xpV =
        reinterpret_cast<const float4*>(x) + (size_t)e1 * NI;

    auto step = [&](float& h, float& c, float x0, float x1) {
        float hh0 = qperm<QP_BCAST0>(h);
        float hh1 = qperm<QP_BCAST1>(h);
        float axA = fmaf(wiA1, x1, fmaf(wiA0, x0, biasA));
        float axB = fmaf(wiB1, x1, fmaf(wiB0, x0, biasB));
        float gA = fmaf(whA1, hh1, fmaf(whA0, hh0, axA));
        float gB = fmaf(whB1, hh1, fmaf(whB0, hh0, axB));
        float nA = fmaf(mA, __builtin_amdgcn_rcpf(1.0f + __builtin_amdgcn_exp2f(aA * gA)), dA);
        float nB = __builtin_amdgcn_rcpf(1.0f + __builtin_amdgcn_exp2f(-LOG2E * gB));
        float xA = qperm<QP_SWAP2>(nA);
        float xB = qperm<QP_SWAP2>(nB);
        c = fmaf(nB, c, nA * xA);
        float tc = 1.0f - 2.0f * __builtin_amdgcn_rcpf(1.0f + __builtin_amdgcn_exp2f((2.0f * LOG2E) * c));
        h = xB * tc;
    };

    constexpr int BV = 4;   // float4s per buffer per chain = 8 timesteps
    float4 AU[BV], AV[BV], BU[BV], BVv[BV];

    auto loadU = [&](float4* buf, int batch) {
#pragma unroll
        for (int j = 0; j < BV; ++j) buf[j] = xpU[batch * BV + j];
    };
    auto loadV = [&](float4* buf, int batch) {
#pragma unroll
        for (int j = 0; j < BV; ++j) buf[j] = xpV[batch * BV + j];
    };
    // interleave the two independent chains step-by-step
    auto consume = [&](const float4* bu, const float4* bv) {
#pragma unroll
        for (int j = 0; j < BV; ++j) {
            step(hU, cU, bu[j].x, bu[j].y);
            step(hV, cV, bv[j].x, bv[j].y);
            step(hU, cU, bu[j].z, bu[j].w);
            step(hV, cV, bv[j].z, bv[j].w);
        }
    };

    const int nb = NI / BV;
    int bi = 0;
    if (nb >= 2) {
        loadU(AU, 0); loadV(AV, 0);
        loadU(BU, 1); loadV(BVv, 1);
        for (bi = 0; bi + 1 < nb; bi += 2) {
            consume(AU, AV);
            if (bi + 2 < nb) { loadU(AU, bi + 2); loadV(AV, bi + 2); }
            consume(BU, BVv);
            if (bi + 3 < nb) { loadU(BU, bi + 3); loadV(BVv, bi + 3); }
        }
        if (bi < nb) { consume(AU, AV); ++bi; }
    }
    for (int i = bi * BV; i < NI; ++i) {   // tail (empty for T=2048)
        float4 u = xpU[i], v = xpV[i];
        step(hU, cU, u.x, u.y);
        step(hV, cV, v.x, v.y);
        step(hU, cU, u.z, u.w);
        step(hV, cV, v.z, v.w);
    }

    if (q < 2) {
        out[2 * e0 + q] = cU;
        out[2 * e1 + q] = cV;
    }
}

extern "C" void kernel_launch(void* const* d_in, const int* in_sizes, int n_in,
                              void* d_out, int out_size, void* d_ws, size_t ws_size,
                              hipStream_t stream) {
    const float* x    = (const float*)d_in[0];
    const float* h0   = (const float*)d_in[1];
    const float* c0   = (const float*)d_in[2];
    const float* w_ih = (const float*)d_in[3];
    const float* w_hh = (const float*)d_in[4];
    const float* b_ih = (const float*)d_in[5];
    const float* b_hh = (const float*)d_in[6];
    float* out = (float*)d_out;

    const int B = in_sizes[1] / 2;           // h0 is (B, H=2)
    const int T = in_sizes[0] / (B * 2);     // x is (B, T, D=2)

    const int threads = (B / 2) * 4;         // 4 lanes per chain pair
    dim3 block(64);
    dim3 grid((threads + 63) / 64);
    hipLaunchKernelGGL(lstm_quad_ilp2_kernel, grid, block, 0, stream,
                       x, h0, c0, w_ih, w_hh, b_ih, b_hh, out, B, T);
}

// Round 6
// 323.740 us; speedup vs baseline: 1.4187x; 1.4187x over previous
//
#include <hip/hip_runtime.h>

// LSTM scan, B=8192 chains, T=2048 steps, D=H=2.
// Round 6: 8 lanes per element (octet = 2 quads). Each lane owns ONE gate
// row. Cross-lane: quad_perm DPP + one ROW_HALF_MIRROR DPP (the only
// cross-quad hop). Both quads redundantly compute c/h so the h-broadcast
// is intra-quad (after one reposition-select for quad1). Per-lane exp2
// scale prefolded into weights; c carried pre-scaled by 2*log2e so
// tanh(c) needs no mul. x via the round-3 register double-buffer
// (2 x 8 float4 = 16 steps/buffer) — the structure the pipeliner likes.
//
// Lane assignment (q = tid&7): l0:i0 l1:i1 l2:f0 l3:f1 l4:o1 l5:o0 l6:g1 l7:g0
// mirror pairs (0-7,1-6,2-5,3-4): i<->g, f<->o.
// After nonlin n and mirror mv:
//   X = (q in {4,5}) ? mv : n ; Y = (q in {2..5}) ? c : mv ; p = X*Y
//   swap2(p) + p -> c (every lane gets its column's c)
//   Z = (q in {4,5}) ? n : mv ; h = Z * tanh(c)
// h lands at l2(h0), l3(h1) in quad0 and l5(h0), l4(h1) in quad1;
// quad_perm(0,1,1,0) repositions quad1 before bcast2/bcast3.

#define LOG2E 1.4426950408889634f

template <int CTRL>
__device__ __forceinline__ float qdpp(float v) {
    int i = __builtin_bit_cast(int, v);
    i = __builtin_amdgcn_update_dpp(0, i, CTRL, 0xf, 0xf, true);
    return __builtin_bit_cast(float, i);
}
#define DPP_HSEL        0x14   // quad_perm(0,1,1,0): local2<-1, local3<-0
#define DPP_BCAST2      0xAA   // quad_perm(2,2,2,2)
#define DPP_BCAST3      0xFF   // quad_perm(3,3,3,3)
#define DPP_SWAP2       0x4E   // quad_perm(2,3,0,1)
#define DPP_HALF_MIRROR 0x141  // row_half_mirror: lane i <-> 7-i per 8

__global__ __launch_bounds__(64, 1) void lstm_oct_kernel(
    const float* __restrict__ x,
    const float* __restrict__ h0,
    const float* __restrict__ c0,
    const float* __restrict__ w_ih,
    const float* __restrict__ w_hh,
    const float* __restrict__ b_ih,
    const float* __restrict__ b_hh,
    float* __restrict__ out,
    int B, int T)
{
    const int tid = blockIdx.x * blockDim.x + threadIdx.x;
    const int e = tid >> 3;        // batch element
    const int q = tid & 7;         // lane within octet
    if (e >= B) return;

    // gate row for this lane (rows 0..7 = i0,i1,f0,f1,g0,g1,o0,o1)
    const int r = (q < 4) ? q : 11 - q;   // l4->7(o1) l5->6(o0) l6->5(g1) l7->4(g0)
    const bool isTanh = (q >= 6);
    const bool inQ1   = (q >= 4);
    const bool sel45  = (q == 4) || (q == 5);
    const bool selMid = (q >= 2) && (q <= 5);

    // exp2 argument scale prefolded into weights: sigma lanes -log2e,
    // tanh lanes +2*log2e. Affine after rcp: sigma (1,0); tanh produces
    // t'(g) = 2*log2e * tanh(g) via (-4L, 2L) so products keep c scaled.
    const float a = isTanh ? (2.0f * LOG2E) : (-LOG2E);
    const float m = isTanh ? (-4.0f * LOG2E) : 1.0f;
    const float d = isTanh ? (2.0f * LOG2E) : 0.0f;

    const float wi0 = w_ih[2 * r] * a, wi1 = w_ih[2 * r + 1] * a;
    const float wh0 = w_hh[2 * r] * a, wh1 = w_hh[2 * r + 1] * a;
    const float bias = (b_ih[r] + b_hh[r]) * a;

    // column this lane's c tracks: l0:0 l1:1 l2:0 l3:1 l4:1 l5:0 l6:1 l7:0
    const int col = (q & 1) ^ ((q >> 2) & 1);
    float h = h0[2 * e + col];
    float c = c0[2 * e + col] * (2.0f * LOG2E);   // scaled cell state

    const int NI = T >> 1;  // float4s per element row (2 timesteps each)
    const float4* __restrict__ xp =
        reinterpret_cast<const float4*>(x) + (size_t)e * NI;

    auto step = [&](float x0, float x1) {
        float hm  = qdpp<DPP_HSEL>(h);
        float hs  = inQ1 ? hm : h;            // reposition quad1's h0,h1
        float hh0 = qdpp<DPP_BCAST2>(hs);
        float hh1 = qdpp<DPP_BCAST3>(hs);
        float ax = fmaf(wi1, x1, fmaf(wi0, x0, bias));  // off-chain
        float g  = fmaf(wh1, hh1, fmaf(wh0, hh0, ax));
        float n  = fmaf(m, __builtin_amdgcn_rcpf(1.0f + __builtin_amdgcn_exp2f(g)), d);
        float mv = qdpp<DPP_HALF_MIRROR>(n);
        float X = sel45  ? mv : n;
        float Y = selMid ? c  : mv;
        float p = X * Y;                      // sigma(i)*t'(g) | sigma(f)*c'
        float ps = qdpp<DPP_SWAP2>(p);
        c = p + ps;                           // scaled c for this lane's col
        // tanh(c) = 1 - 2*rcp(1+exp2(c')) since c' = 2*log2e*c
        float tc = fmaf(-2.0f, __builtin_amdgcn_rcpf(1.0f + __builtin_amdgcn_exp2f(c)), 1.0f);
        float Z = sel45 ? n : mv;             // sigma(o)
        h = Z * tc;                           // valid at l2,l3 / l5,l4
    };

    constexpr int BV = 8;              // float4s per buffer = 16 timesteps
    float4 A[BV], Bb[BV];

    auto loadbuf = [&](float4* buf, int batch) {
#pragma unroll
        for (int j = 0; j < BV; ++j) buf[j] = xp[batch * BV + j];
    };
    auto consume = [&](const float4* buf) {
#pragma unroll
        for (int j = 0; j < BV; ++j) {
            step(buf[j].x, buf[j].y);
            step(buf[j].z, buf[j].w);
        }
    };

    const int nb = NI / BV;
    int bi = 0;
    if (nb >= 2) {
        loadbuf(A, 0);
        loadbuf(Bb, 1);
        for (bi = 0; bi + 1 < nb; bi += 2) {
            consume(A);
            if (bi + 2 < nb) loadbuf(A, bi + 2);
            consume(Bb);
            if (bi + 3 < nb) loadbuf(Bb, bi + 3);
        }
        if (bi < nb) { consume(A); ++bi; }
    }
    for (int i = bi * BV; i < NI; ++i) {   // tail (empty for T=2048)
        float4 v = xp[i];
        step(v.x, v.y);
        step(v.z, v.w);
    }

    // unscale: c = c' * ln2/2 ; l0 holds col0, l1 holds col1
    if (q < 2) out[2 * e + q] = c * (0.5f / LOG2E);
}

extern "C" void kernel_launch(void* const* d_in, const int* in_sizes, int n_in,
                              void* d_out, int out_size, void* d_ws, size_t ws_size,
                              hipStream_t stream) {
    const float* x    = (const float*)d_in[0];
    const float* h0   = (const float*)d_in[1];
    const float* c0   = (const float*)d_in[2];
    const float* w_ih = (const float*)d_in[3];
    const float* w_hh = (const float*)d_in[4];
    const float* b_ih = (const float*)d_in[5];
    const float* b_hh = (const float*)d_in[6];
    float* out = (float*)d_out;

    const int B = in_sizes[1] / 2;           // h0 is (B, H=2)
    const int T = in_sizes[0] / (B * 2);     // x is (B, T, D=2)

    const int threads = B * 8;               // 8 lanes per element
    dim3 block(64);
    dim3 grid((threads + 63) / 64);
    hipLaunchKernelGGL(lstm_oct_kernel, grid, block, 0, stream,
                       x, h0, c0, w_ih, w_hh, b_ih, b_hh, out, B, T);
}

// Round 7
// 322.210 us; speedup vs baseline: 1.4254x; 1.0047x over previous
//
#include <hip/hip_runtime.h>

// LSTM scan, B=8192 chains, T=2048 steps, D=H=2. 8 lanes/element.
// Round 7: chain-shortening rewrite. h is never materialized: the gate
// uses g = W_other*tc_other + W_own*tc_own + AX, where W_* = a*wh*sigma(o)
// are built OFF-CHAIN during the tanh(c) trans window (bank-masked DPP
// broadcasts of sigma(o), weight mul folded). tanh(c) via the exp2-product
// trick: exp2(c') = exp2(p)*swap(exp2(p)) so exp2 starts at p, before the
// cross-lane add. c carried scaled by 2*log2e. x via round-3 register
// double-buffer (2 x 8 float4 = 16 steps/buffer).
//
// Lanes (q=tid&7): l0:i0 l1:i1 l2:f0 l3:f1 l4:o1 l5:o0 l6:g1 l7:g0
// mirror pairs (0,7)(1,6)(2,5)(3,4) = i<->g, f<->o.
// col(l) = (q&1)^((q>>2)&1): l0:0 l1:1 l2:0 l3:1 l4:1 l5:0 l6:1 l7:0.

#define LOG2E 1.4426950408889634f

template <int CTRL>
__device__ __forceinline__ float qdpp(float v) {
    int i = __builtin_bit_cast(int, v);
    i = __builtin_amdgcn_update_dpp(0, i, CTRL, 0xF, 0xF, true);
    return __builtin_bit_cast(float, i);
}
// masked merge DPP: lanes outside row/bank mask keep `old`
template <int CTRL, int BANK>
__device__ __forceinline__ float mdpp(float old, float v) {
    int i = __builtin_amdgcn_update_dpp(__builtin_bit_cast(int, old),
                                        __builtin_bit_cast(int, v),
                                        CTRL, 0xF, BANK, false);
    return __builtin_bit_cast(float, i);
}
#define DPP_MIRROR8 0x141  // row_half_mirror: lane i <-> 7-i
#define DPP_SWAP2   0x4E   // quad_perm(2,3,0,1)
#define DPP_COLSWP  0xB1   // quad_perm(1,0,3,2): adjacent-lane (other col)
#define DPP_ZB_OWN0 0xEE   // quad_perm(2,3,2,3)  (quads0: sigma_o own-col)
#define DPP_ZB_OWN1 0x44   // quad_perm(0,1,0,1)  (quads1)
#define DPP_ZB_OTH0 0xBB   // quad_perm(3,2,3,2)
#define DPP_ZB_OTH1 0x11   // quad_perm(1,0,1,0)

__global__ __launch_bounds__(64, 1) void lstm_oct_nh_kernel(
    const float* __restrict__ x,
    const float* __restrict__ h0,
    const float* __restrict__ c0,
    const float* __restrict__ w_ih,
    const float* __restrict__ w_hh,
    const float* __restrict__ b_ih,
    const float* __restrict__ b_hh,
    float* __restrict__ out,
    int B, int T)
{
    const int tid = blockIdx.x * blockDim.x + threadIdx.x;
    const int e = tid >> 3;
    const int q = tid & 7;
    if (e >= B) return;

    const int r = (q < 4) ? q : 11 - q;   // gate row (i0,i1,f0,f1,g0,g1,o0,o1)
    const bool isTanh = (q >= 6);
    const bool sel45  = (q == 4) || (q == 5);
    const bool selMid = (q >= 2) && (q <= 5);
    const int col = (q & 1) ^ ((q >> 2) & 1);

    // exp2 arg scale: sigma lanes -log2e, tanh lanes +2*log2e (prefolded).
    // nonlin: n = m*rcp(1+exp2(garg)) + d ; tanh lanes emit 2L*tanh(g).
    const float a = isTanh ? (2.0f * LOG2E) : (-LOG2E);
    const float m = isTanh ? (-4.0f * LOG2E) : 1.0f;
    const float d = isTanh ? (2.0f * LOG2E) : 0.0f;

    const float wx0 = w_ih[2 * r] * a, wx1 = w_ih[2 * r + 1] * a;
    const float bias = (b_ih[r] + b_hh[r]) * a;
    const float AwhOwn = w_hh[2 * r + col] * a;
    const float AwhOth = w_hh[2 * r + (1 - col)] * a;

    // Loop state: tc (tanh(c) own col; seeded with h0 so step 1 is exact),
    // cs (c scaled by 2L), WOwn/WOth (a*wh*sigma_o; seeded sigma_o = 1).
    float tc = h0[2 * e + col];
    float cs = c0[2 * e + col] * (2.0f * LOG2E);
    float WOwn = AwhOwn;
    float WOth = AwhOth;

    const int NI = T >> 1;
    const float4* __restrict__ xp =
        reinterpret_cast<const float4*>(x) + (size_t)e * NI;

    auto step = [&](float x0, float x1) {
        // ---- chain: gate from carried (tc, W) ----
        float tco = qdpp<DPP_COLSWP>(tc);            // other col's tanh(c)
        float ax  = fmaf(wx1, x1, fmaf(wx0, x0, bias));   // off-chain
        float g   = fmaf(WOth, tco, fmaf(WOwn, tc, ax));
        float n   = fmaf(m, __builtin_amdgcn_rcpf(1.0f + __builtin_amdgcn_exp2f(g)), d);
        float mv  = qdpp<DPP_MIRROR8>(n);
        float X = sel45 ? mv : n;                    // sigma_i|sigma_f|t'g side
        float Y = selMid ? cs : mv;                  // c' | partner nonlin
        float p = X * Y;
        // c update (off main chain; needed next step + epilogue)
        float ps = qdpp<DPP_SWAP2>(p);
        cs = p + ps;
        // tanh(c) via exp2-product: exp2(cs) = exp2(p)*swap(exp2(p))
        float Ep  = __builtin_amdgcn_exp2f(p);
        float Eps = qdpp<DPP_SWAP2>(Ep);
        float r2  = __builtin_amdgcn_rcpf(fmaf(Ep, Eps, 1.0f));
        tc = fmaf(-2.0f, r2, 1.0f);
        // ---- off-chain (fills the trans window): next-step W from sigma_o
        float Z = sel45 ? n : mv;                    // sigma_o at locals 2,3 / 0,1
        float zbOwn = mdpp<DPP_ZB_OWN0, 0x5>(Z, Z);
        zbOwn = mdpp<DPP_ZB_OWN1, 0xA>(zbOwn, Z);
        float zbOth = mdpp<DPP_ZB_OTH0, 0x5>(Z, Z);
        zbOth = mdpp<DPP_ZB_OTH1, 0xA>(zbOth, Z);
        WOwn = AwhOwn * zbOwn;
        WOth = AwhOth * zbOth;
    };

    constexpr int BV = 8;              // float4s per buffer = 16 timesteps
    float4 A[BV], Bb[BV];

    auto loadbuf = [&](float4* buf, int batch) {
#pragma unroll
        for (int j = 0; j < BV; ++j) buf[j] = xp[batch * BV + j];
    };
    auto consume = [&](const float4* buf) {
#pragma unroll
        for (int j = 0; j < BV; ++j) {
            step(buf[j].x, buf[j].y);
            step(buf[j].z, buf[j].w);
        }
    };

    const int nb = NI / BV;
    int bi = 0;
    if (nb >= 2) {
        loadbuf(A, 0);
        loadbuf(Bb, 1);
        for (bi = 0; bi + 1 < nb; bi += 2) {
            consume(A);
            if (bi + 2 < nb) loadbuf(A, bi + 2);
            consume(Bb);
            if (bi + 3 < nb) loadbuf(Bb, bi + 3);
        }
        if (bi < nb) { consume(A); ++bi; }
    }
    for (int i = bi * BV; i < NI; ++i) {   // tail (empty for T=2048)
        float4 v = xp[i];
        step(v.x, v.y);
        step(v.z, v.w);
    }

    // cs = 2L*c -> c = cs * ln2/2
    if (q < 2) out[2 * e + q] = cs * (0.5f / LOG2E);
}

extern "C" void kernel_launch(void* const* d_in, const int* in_sizes, int n_in,
                              void* d_out, int out_size, void* d_ws, size_t ws_size,
                              hipStream_t stream) {
    const float* x    = (const float*)d_in[0];
    const float* h0   = (const float*)d_in[1];
    const float* c0   = (const float*)d_in[2];
    const float* w_ih = (const float*)d_in[3];
    const float* w_hh = (const float*)d_in[4];
    const float* b_ih = (const float*)d_in[5];
    const float* b_hh = (const float*)d_in[6];
    float* out = (float*)d_out;

    const int B = in_sizes[1] / 2;           // h0 is (B, H=2)
    const int T = in_sizes[0] / (B * 2);     // x is (B, T, D=2)

    const int threads = B * 8;               // 8 lanes per element
    dim3 block(64);
    dim3 grid((threads + 63) / 64);
    hipLaunchKernelGGL(lstm_oct_nh_kernel, grid, block, 0, stream,
                       x, h0, c0, w_ih, w_hh, b_ih, b_hh, out, B, T);
}